// Round 1
// baseline (1548.042 us; speedup 1.0000x reference)
//
#include <hip/hip_runtime.h>
#include <hip/hip_bf16.h>

// SSN soft superpixel clustering, MI355X (gfx950).
// x: [B=2, C=5, H=512, W=512] fp32; K=256 superpixels; 10 EM iterations.
// Output: soft assignment transposed [B, K, N] fp32 (512 MiB).
//
// Math: softmax_k(-(p2 + c2 - 2 dot)) == softmax_k(2 dot - c2)   (p2 drops).
// Precompute per-k table row[8] = {2*L*c0..2*L*c4, -L*||c||^2, 0, 0}, L=log2(e),
// so logit_for_exp2 = row[5] + sum_c row[c]*pix_c and aff = exp2(logit)/S.

#define B_ 2
#define C_ 5
#define H_ 512
#define W_ 512
#define N_ (H_*W_)          // 262144
#define K_ 256
#define NITER_ 10
#define T_ 512              // pixels per step-kernel block
#define LOG2E 1.4426950408889634f

typedef float f32x8 __attribute__((ext_vector_type(8)));
typedef float f32x4 __attribute__((ext_vector_type(4)));

// ---------------------------------------------------------------------------
// Kernel 1: grid-init centers = 32x32 block means, written as scaled table.
// grid = B*K blocks x 256 threads.
__global__ __launch_bounds__(256) void init_centers(const float* __restrict__ x,
                                                    float* __restrict__ ctab) {
    int bk  = blockIdx.x;            // 0..511
    int b   = bk >> 8;
    int k   = bk & (K_ - 1);
    int gy  = k >> 4, gx = k & 15;   // 16x16 grid of 32x32 blocks
    int tid = threadIdx.x;

    float s[C_] = {0.f, 0.f, 0.f, 0.f, 0.f};
    for (int i = tid; i < 1024; i += 256) {          // 4 pixels per thread
        int py = i >> 5, px = i & 31;
        int n  = (gy * 32 + py) * W_ + gx * 32 + px;
        const float* xb = x + (size_t)b * C_ * N_ + n;
        #pragma unroll
        for (int c = 0; c < C_; c++) s[c] += xb[(size_t)c * N_];
    }
    // wave (64-lane) reduce, then cross-wave via LDS
    #pragma unroll
    for (int c = 0; c < C_; c++) {
        #pragma unroll
        for (int off = 32; off > 0; off >>= 1)
            s[c] += __shfl_down(s[c], off, 64);
    }
    __shared__ float wred[4][C_];
    int lane = tid & 63, wid = tid >> 6;
    if (lane == 0) {
        #pragma unroll
        for (int c = 0; c < C_; c++) wred[wid][c] = s[c];
    }
    __syncthreads();
    if (tid == 0) {
        float m[C_]; float c2 = 0.f;
        #pragma unroll
        for (int c = 0; c < C_; c++) {
            m[c] = (wred[0][c] + wred[1][c] + wred[2][c] + wred[3][c]) * (1.0f / 1024.0f);
            c2  += m[c] * m[c];
        }
        float* row = ctab + (size_t)(b * K_ + k) * 8;
        #pragma unroll
        for (int c = 0; c < C_; c++) row[c] = 2.0f * LOG2E * m[c];
        row[5] = -LOG2E * c2;
        row[6] = 0.f; row[7] = 0.f;
    }
}

// ---------------------------------------------------------------------------
// Kernel 2: one EM step. Phase A: per-pixel softmax denom (centers via
// wave-uniform scalar loads). Phase B: k-per-thread register reduction of
// wsum[k] and csum[c][k] over the block's pixel tile, 6 atomics per thread.
// grid = B * (N/T_) = 1024 blocks x 256 threads.
__global__ __launch_bounds__(256, 4) void step_kernel(const float* __restrict__ x,
                                                      const float* __restrict__ ctab,
                                                      float* __restrict__ acc) {
    __shared__ float pl[C_][T_];
    __shared__ float rs[T_];
    int bid = blockIdx.x;
    int b   = bid >> 9;                 // 512 blocks per batch
    int n0  = (bid & 511) * T_;
    int tid = threadIdx.x;

    const float* xb = x + (size_t)b * C_ * N_ + n0;
    #pragma unroll
    for (int c = 0; c < C_; c++) {
        pl[c][tid]       = xb[(size_t)c * N_ + tid];
        pl[c][tid + 256] = xb[(size_t)c * N_ + tid + 256];
    }
    __syncthreads();

    // ---- phase A: two pixels per thread share each center-table row ----
    float p0[C_], p1[C_];
    #pragma unroll
    for (int c = 0; c < C_; c++) { p0[c] = pl[c][tid]; p1[c] = pl[c][tid + 256]; }

    const f32x8* crow = (const f32x8*)(ctab + (size_t)b * K_ * 8);
    float S0 = 0.f, S1 = 0.f;
    #pragma unroll 8
    for (int k = 0; k < K_; k++) {
        f32x8 r = crow[k];               // wave-uniform -> s_load_dwordx8
        float l0 = r[5], l1 = r[5];
        l0 = fmaf(r[0], p0[0], l0);  l1 = fmaf(r[0], p1[0], l1);
        l0 = fmaf(r[1], p0[1], l0);  l1 = fmaf(r[1], p1[1], l1);
        l0 = fmaf(r[2], p0[2], l0);  l1 = fmaf(r[2], p1[2], l1);
        l0 = fmaf(r[3], p0[3], l0);  l1 = fmaf(r[3], p1[3], l1);
        l0 = fmaf(r[4], p0[4], l0);  l1 = fmaf(r[4], p1[4], l1);
        S0 += __builtin_amdgcn_exp2f(l0);
        S1 += __builtin_amdgcn_exp2f(l1);
    }
    rs[tid]       = 1.0f / S0;
    rs[tid + 256] = 1.0f / S1;
    __syncthreads();

    // ---- phase B: thread owns k = tid; pixel data broadcast from LDS ----
    const float* myrow = ctab + (size_t)(b * K_ + tid) * 8;
    f32x4 r0 = *(const f32x4*)(myrow);
    f32x4 r1 = *(const f32x4*)(myrow + 4);
    float c0 = r0[0], c1 = r0[1], c2v = r0[2], c3 = r0[3], c4 = r1[0], nc2 = r1[1];

    float a0 = 0.f, a1 = 0.f, a2 = 0.f, a3 = 0.f, a4 = 0.f, aw = 0.f;
    #pragma unroll 4
    for (int p = 0; p < T_; p++) {
        float q0 = pl[0][p], q1 = pl[1][p], q2 = pl[2][p];
        float q3 = pl[3][p], q4 = pl[4][p], rr = rs[p];   // same-addr broadcast
        float l = nc2;
        l = fmaf(c0, q0, l); l = fmaf(c1, q1, l); l = fmaf(c2v, q2, l);
        l = fmaf(c3, q3, l); l = fmaf(c4, q4, l);
        float af = __builtin_amdgcn_exp2f(l) * rr;
        aw += af;
        a0 = fmaf(q0, af, a0); a1 = fmaf(q1, af, a1); a2 = fmaf(q2, af, a2);
        a3 = fmaf(q3, af, a3); a4 = fmaf(q4, af, a4);
    }
    float* ab = acc + (size_t)b * 6 * K_ + tid;
    unsafeAtomicAdd(ab + 0 * K_, a0);   // native global_atomic_add_f32
    unsafeAtomicAdd(ab + 1 * K_, a1);
    unsafeAtomicAdd(ab + 2 * K_, a2);
    unsafeAtomicAdd(ab + 3 * K_, a3);
    unsafeAtomicAdd(ab + 4 * K_, a4);
    unsafeAtomicAdd(ab + 5 * K_, aw);
}

// ---------------------------------------------------------------------------
// Kernel 3: centers <- csum / (wsum + 1e-16), rewritten as scaled table.
// grid = B blocks x 256 threads.
__global__ __launch_bounds__(256) void update_centers(const float* __restrict__ acc,
                                                      float* __restrict__ ctab) {
    int b = blockIdx.x;
    int k = threadIdx.x;
    const float* ab = acc + (size_t)b * 6 * K_ + k;
    float w = ab[5 * K_] + 1e-16f;
    float m[C_]; float c2 = 0.f;
    #pragma unroll
    for (int c = 0; c < C_; c++) { m[c] = ab[(size_t)c * K_] / w; c2 += m[c] * m[c]; }
    float* row = ctab + (size_t)(b * K_ + k) * 8;
    #pragma unroll
    for (int c = 0; c < C_; c++) row[c] = 2.0f * LOG2E * m[c];
    row[5] = -LOG2E * c2;
    row[6] = 0.f; row[7] = 0.f;
}

// ---------------------------------------------------------------------------
// Kernel 4: final affinity, written transposed [B, K, N]. Pixel-per-lane so
// stores along n are coalesced. grid = B*N/256 blocks x 256 threads.
__global__ __launch_bounds__(256, 4) void final_kernel(const float* __restrict__ x,
                                                       const float* __restrict__ ctab,
                                                       float* __restrict__ out) {
    size_t gid = (size_t)blockIdx.x * 256 + threadIdx.x;   // 0..B*N-1
    int b = (int)(gid >> 18);                              // N_ == 2^18
    int n = (int)(gid & (size_t)(N_ - 1));

    const float* xb = x + (size_t)b * C_ * N_ + n;
    float p[C_];
    #pragma unroll
    for (int c = 0; c < C_; c++) p[c] = xb[(size_t)c * N_];

    const f32x8* crow = (const f32x8*)(ctab + (size_t)b * K_ * 8);
    float S = 0.f;
    #pragma unroll 8
    for (int k = 0; k < K_; k++) {
        f32x8 r = crow[k];
        float l = r[5];
        l = fmaf(r[0], p[0], l); l = fmaf(r[1], p[1], l); l = fmaf(r[2], p[2], l);
        l = fmaf(r[3], p[3], l); l = fmaf(r[4], p[4], l);
        S += __builtin_amdgcn_exp2f(l);
    }
    float rS = 1.0f / S;

    float* ob = out + (size_t)b * K_ * N_ + n;
    #pragma unroll 4
    for (int k = 0; k < K_; k++) {
        f32x8 r = crow[k];
        float l = r[5];
        l = fmaf(r[0], p[0], l); l = fmaf(r[1], p[1], l); l = fmaf(r[2], p[2], l);
        l = fmaf(r[3], p[3], l); l = fmaf(r[4], p[4], l);
        ob[(size_t)k * N_] = __builtin_amdgcn_exp2f(l) * rS;   // coalesced in n
    }
}

// ---------------------------------------------------------------------------
extern "C" void kernel_launch(void* const* d_in, const int* in_sizes, int n_in,
                              void* d_out, int out_size, void* d_ws, size_t ws_size,
                              hipStream_t stream) {
    const float* x = (const float*)d_in[0];
    // d_in[1] = nspix (=256), d_in[2] = n_iter (=10): fixed by setup_inputs,
    // compiled in as constants (device-side scalars can't be read during capture).
    float* out  = (float*)d_out;
    float* ctab = (float*)d_ws;                       // B*K*8 = 4096 floats
    float* acc  = ctab + (size_t)B_ * K_ * 8;         // NITER slots x B*6*K

    // ws is re-poisoned to 0xAA before every timed call: zero the accumulators.
    hipMemsetAsync(acc, 0, (size_t)NITER_ * B_ * 6 * K_ * sizeof(float), stream);

    init_centers<<<B_ * K_, 256, 0, stream>>>(x, ctab);
    for (int s = 0; s < NITER_; s++) {
        float* as = acc + (size_t)s * B_ * 6 * K_;
        step_kernel<<<B_ * (N_ / T_), 256, 0, stream>>>(x, ctab, as);
        update_centers<<<B_, 256, 0, stream>>>(as, ctab);
    }
    final_kernel<<<(B_ * N_) / 256, 256, 0, stream>>>(x, ctab, out);
}